// Round 6
// baseline (2453.091 us; speedup 1.0000x reference)
//
#include <hip/hip_runtime.h>
#include <math.h>

namespace {

constexpr int N_  = 32768;   // nodes
constexpr int S_  = 1024;    // nodes per graph
constexpr int B_  = 32;      // graphs
constexpr int E_  = 262144;  // edges
constexpr int C_  = 128;     // hidden
constexpr int ND_ = 64;
constexpr int PE_ = 16;
constexpr int ED_ = 16;
constexpr float LNE = 1e-5f;

typedef __attribute__((ext_vector_type(8))) short short8;
typedef __attribute__((ext_vector_type(4))) float floatx4;

__device__ inline float gelu_tanh(float v) {
  const float c = 0.7978845608028654f;
  return 0.5f * v * (1.0f + tanhf(c * (v + 0.044715f * v * v * v)));
}

__device__ inline unsigned short f2bf_u(float f) {
  unsigned u = __float_as_uint(f);
  u += 0x7fff + ((u >> 16) & 1);
  return (unsigned short)(u >> 16);
}

__device__ inline float block_sum128(float v, float* red, int t) {
  red[t] = v;
  __syncthreads();
#pragma unroll
  for (int off = 64; off > 0; off >>= 1) {
    if (t < off) red[t] += red[t + off];
    __syncthreads();
  }
  float r = red[0];
  __syncthreads();
  return r;
}

// ---------------- zero (graph-capture-safe memset) ----------------
__global__ void k_zero(float4* __restrict__ p, int n4) {
  int i = blockIdx.x * 256 + threadIdx.x;
  if (i < n4) p[i] = make_float4(0.f, 0.f, 0.f, 0.f);
}

// ---------------- counting sort by dst: hist -> scan -> scatter ----------------
__global__ void k_count(const int* __restrict__ dst, int* __restrict__ hist) {
  int e = blockIdx.x * 256 + threadIdx.x;
  if (e < E_) atomicAdd(&hist[dst[e]], 1);
}

// 1 block, 1024 threads; 32 bins/thread. Writes binStart[32769]; hist becomes cursor.
__global__ __launch_bounds__(1024) void k_scan(int* __restrict__ hist, int* __restrict__ binStart) {
  __shared__ int sums[1024];
  int t = threadIdx.x;
  int base = t * 32;
  int loc[32];
  int s = 0;
#pragma unroll
  for (int i = 0; i < 32; ++i) { loc[i] = s; s += hist[base + i]; }
  sums[t] = s;
  __syncthreads();
  for (int off = 1; off < 1024; off <<= 1) {
    int v = (t >= off) ? sums[t - off] : 0;
    __syncthreads();
    sums[t] += v;
    __syncthreads();
  }
  int excl = sums[t] - s;
#pragma unroll
  for (int i = 0; i < 32; ++i) {
    int v = excl + loc[i];
    binStart[base + i] = v;
    hist[base + i] = v;  // cursor (in-place)
  }
  if (t == 1023) binStart[32768] = sums[1023];
}

__global__ void k_scatter(const int* __restrict__ dst, int* __restrict__ cursor,
                          int* __restrict__ perm) {
  int e = blockIdx.x * 256 + threadIdx.x;
  if (e < E_) {
    int p = atomicAdd(&cursor[dst[e]], 1);
    perm[p] = e;
  }
}

// ---------------- fold edge_w2 into elin; emit TRANSPOSED bf16 weight ----------------
__global__ void k_fuse_w(const float* __restrict__ w2, const float* __restrict__ b2,
                         const float* __restrict__ elin_w, const float* __restrict__ elin_b,
                         unsigned short* __restrict__ fw2t, float* __restrict__ fb2) {
  int t = threadIdx.x;
  int bid = blockIdx.x;
  int layer = bid / (C_ + 1);
  int k = bid % (C_ + 1);
  const float* el = elin_w + (size_t)layer * C_ * C_;
  if (k < C_) {
    float a = 0.0f;
    for (int m = 0; m < C_; ++m) a += w2[k * C_ + m] * el[m * C_ + t];
    fw2t[(size_t)layer * C_ * C_ + t * C_ + k] = f2bf_u(a);
  } else {
    float a = elin_b[layer * C_ + t];
    for (int m = 0; m < C_; ++m) a += b2[m] * el[m * C_ + t];
    fb2[layer * C_ + t] = a;
  }
}

// ---------------- prep: bf16-transpose all node-path weights ----------------
__global__ void k_prep(const float* __restrict__ gin_w1, const float* __restrict__ gin_w2,
                       const float* __restrict__ aqkv_w, const float* __restrict__ aout_w,
                       const float* __restrict__ mlp_w1, const float* __restrict__ mlp_w2,
                       unsigned short* __restrict__ wt) {
  int t = threadIdx.x;
  int bid = blockIdx.x;
  int l = bid / 1152;
  int r = bid % 1152;
  unsigned short* base = wt + (size_t)l * 163840;
  if (r < 128) {
    base[r * 128 + t] = f2bf_u(gin_w1[(size_t)l * 16384 + t * 128 + r]);
  } else if (r < 256) {
    int n = r - 128;
    base[16384 + n * 128 + t] = f2bf_u(gin_w2[(size_t)l * 16384 + t * 128 + n]);
  } else if (r < 640) {
    int n = r - 256;
    base[32768 + n * 128 + t] = f2bf_u(aqkv_w[(size_t)l * 49152 + t * 384 + n]);
  } else if (r < 768) {
    int n = r - 640;
    base[81920 + n * 128 + t] = f2bf_u(aout_w[(size_t)l * 16384 + t * 128 + n]);
  } else if (r < 1024) {
    int n = r - 768;
    base[98304 + n * 128 + t] = f2bf_u(mlp_w1[(size_t)l * 32768 + t * 256 + n]);
  } else {
    int n = r - 1024;
    base[131072 + n * 256 + t]       = f2bf_u(mlp_w2[(size_t)l * 32768 + t * 128 + n]);
    base[131072 + n * 256 + 128 + t] = f2bf_u(mlp_w2[(size_t)l * 32768 + (t + 128) * 128 + n]);
  }
}

// ---------------- node encoder (scalar fp32) ----------------
__global__ void k_node_enc(const float* __restrict__ xin, const float* __restrict__ pe,
                           const float* __restrict__ w1, const float* __restrict__ b1,
                           const float* __restrict__ w2, const float* __restrict__ b2,
                           float* __restrict__ xout) {
  __shared__ float inL[4][80];
  __shared__ float hidL[4][C_];
  int t = threadIdx.x;
  int row0 = blockIdx.x * 4;
#pragma unroll
  for (int r = 0; r < 4; ++r) {
    int row = row0 + r;
    if (t < ND_) inL[r][t] = xin[(size_t)row * ND_ + t];
    else if (t < 80) inL[r][t] = pe[(size_t)row * PE_ + (t - ND_)];
  }
  __syncthreads();
  float acc[4];
  float bb = b1[t];
#pragma unroll
  for (int r = 0; r < 4; ++r) acc[r] = bb;
  for (int k = 0; k < 80; ++k) {
    float wv = w1[k * C_ + t];
#pragma unroll
    for (int r = 0; r < 4; ++r) acc[r] += inL[r][k] * wv;
  }
#pragma unroll
  for (int r = 0; r < 4; ++r) hidL[r][t] = fmaxf(acc[r], 0.0f);
  __syncthreads();
  float bb2 = b2[t];
#pragma unroll
  for (int r = 0; r < 4; ++r) acc[r] = bb2;
  for (int k = 0; k < C_; ++k) {
    float wv = w2[k * C_ + t];
#pragma unroll
    for (int r = 0; r < 4; ++r) acc[r] += hidL[r][k] * wv;
  }
#pragma unroll
  for (int r = 0; r < 4; ++r) xout[(size_t)(row0 + r) * C_ + t] = acc[r];
}

// ------------- FUSED edge pipeline + GIN (sorted edges, LDS aggregation, no atomics to HBM)
// Block = 64 dst nodes; its sorted-edge range from binStart. Per 64-edge chunk:
// hidden=relu(ea@ew1+eb1) -> MFMA vs fw2t -> msg=relu(acc+fb2+x[src]) -> ds_add into aggL.
// Then GIN: hl = LN1(MLP2((1+eps)x + aggL) + x).
__global__ __launch_bounds__(256) void k_edge_gin(
    const float* __restrict__ ea, const float* __restrict__ x,
    const int* __restrict__ src, const int* __restrict__ dst,
    const int* __restrict__ perm, const int* __restrict__ binStart,
    const float* __restrict__ ew1, const float* __restrict__ eb1,
    const unsigned short* __restrict__ fw2t, const float* __restrict__ fb2,
    const unsigned short* __restrict__ gw1t, const float* __restrict__ gb1,
    const unsigned short* __restrict__ gw2t, const float* __restrict__ gb2,
    const float* __restrict__ g, const float* __restrict__ bln,
    const float* __restrict__ epsarr, int layer,
    float* __restrict__ hl) {
  __shared__ float aggL[64][128];           // 32 KB
  __shared__ float eaL[64][ED_];            // 4 KB
  __shared__ unsigned short hidB[64][136];  // 17.4 KB (edge hidden, then gin hidden)
  __shared__ unsigned short inB[64][136];   // 17.4 KB (gin input)
  __shared__ int srcL[64], dstL[64];
  int tid = threadIdx.x;
  int node0 = blockIdx.x * 64;
  int eStart = binStart[node0];
  int eEnd = binStart[node0 + 64];

#pragma unroll
  for (int i = 0; i < 8; ++i)
    ((float4*)aggL)[i * 256 + tid] = make_float4(0.f, 0.f, 0.f, 0.f);

  int lane = tid & 63, w = tid >> 6, li = lane & 15, quad = lane >> 4;
  int r0 = w * 16;

  float fbv[8];
#pragma unroll
  for (int t8 = 0; t8 < 8; ++t8) fbv[t8] = fb2[t8 * 16 + li];

  for (int e0 = eStart; e0 < eEnd; e0 += 64) {
    int cnt = min(64, eEnd - e0);
    __syncthreads();  // protect eaL/hidB/srcL from previous iteration's readers
    if (tid < 64 && tid < cnt) {
      int e = perm[e0 + tid];
      srcL[tid] = src[e];
      dstL[tid] = dst[e];
    }
    {
      int r = tid >> 2, c4 = tid & 3;
      if (r < cnt) {
        int e = perm[e0 + r];
        ((float4*)&eaL[r][0])[c4] = ((const float4*)(ea + (size_t)e * ED_))[c4];
      }
    }
    __syncthreads();
    // hidden = relu(ea @ ew1 + eb1), bf16 into hidB
    {
      int col = tid & 127;
      int rh = (tid >> 7) * 32;
      float acch[32];
      float bb = eb1[col];
#pragma unroll
      for (int rr = 0; rr < 32; ++rr) acch[rr] = bb;
      for (int k = 0; k < ED_; ++k) {
        float wv = ew1[k * C_ + col];
#pragma unroll
        for (int rr = 0; rr < 32; ++rr) acch[rr] += eaL[rh + rr][k] * wv;
      }
#pragma unroll
      for (int rr = 0; rr < 32; ++rr) hidB[rh + rr][col] = f2bf_u(fmaxf(acch[rr], 0.0f));
    }
    __syncthreads();
    short8 aK[4];
#pragma unroll
    for (int k4 = 0; k4 < 4; ++k4)
      aK[k4] = *(const short8*)&hidB[r0 + li][k4 * 32 + quad * 8];
    floatx4 acc[8];
#pragma unroll
    for (int t8 = 0; t8 < 8; ++t8) acc[t8] = (floatx4){0.f, 0.f, 0.f, 0.f};
#pragma unroll
    for (int t8 = 0; t8 < 8; ++t8) {
      const unsigned short* bp = fw2t + (size_t)(t8 * 16 + li) * C_ + quad * 8;
#pragma unroll
      for (int k4 = 0; k4 < 4; ++k4) {
        short8 bf = *(const short8*)(bp + k4 * 32);
        acc[t8] = __builtin_amdgcn_mfma_f32_16x16x32_bf16(aK[k4], bf, acc[t8], 0, 0, 0);
      }
    }
#pragma unroll
    for (int reg = 0; reg < 4; ++reg) {
      int cr = r0 + quad * 4 + reg;
      if (cr < cnt) {
        const float* xs = x + (size_t)srcL[cr] * C_;
        int dl = dstL[cr] - node0;
#pragma unroll
        for (int t8 = 0; t8 < 8; ++t8) {
          int n = t8 * 16 + li;
          float v = fmaxf(acc[t8][reg] + fbv[t8] + xs[n], 0.0f);
          atomicAdd(&aggL[dl][n], v);  // LDS atomic
        }
      }
    }
  }
  __syncthreads();

  // ---- GIN phase: in = bf16((1+eps)x + agg) ----
  float epsv = 1.0f + epsarr[layer];
#pragma unroll
  for (int i = 0; i < 8; ++i) {
    int p = i * 256 + tid;
    int r = p >> 5, c4 = p & 31;
    float4 xa = *(const float4*)(x + (size_t)(node0 + r) * C_ + c4 * 4);
    float4 ag = *(const float4*)&aggL[r][c4 * 4];
    ushort4 u;
    u.x = f2bf_u(epsv * xa.x + ag.x);
    u.y = f2bf_u(epsv * xa.y + ag.y);
    u.z = f2bf_u(epsv * xa.z + ag.z);
    u.w = f2bf_u(epsv * xa.w + ag.w);
    *(ushort4*)&inB[r][c4 * 4] = u;
  }
  __syncthreads();
  short8 aK[4];
#pragma unroll
  for (int k4 = 0; k4 < 4; ++k4) aK[k4] = *(const short8*)&inB[r0 + li][k4 * 32 + quad * 8];
  floatx4 acc1[8];
#pragma unroll
  for (int t8 = 0; t8 < 8; ++t8) acc1[t8] = (floatx4){0.f, 0.f, 0.f, 0.f};
#pragma unroll
  for (int t8 = 0; t8 < 8; ++t8) {
    const unsigned short* bp = gw1t + (size_t)(t8 * 16 + li) * 128 + quad * 8;
#pragma unroll
    for (int k4 = 0; k4 < 4; ++k4) {
      short8 bf = *(const short8*)(bp + k4 * 32);
      acc1[t8] = __builtin_amdgcn_mfma_f32_16x16x32_bf16(aK[k4], bf, acc1[t8], 0, 0, 0);
    }
  }
  // bias + relu -> hidB (wave-private rows)
#pragma unroll
  for (int t8 = 0; t8 < 8; ++t8) {
    float bv = gb1[t8 * 16 + li];
#pragma unroll
    for (int reg = 0; reg < 4; ++reg)
      hidB[r0 + quad * 4 + reg][t8 * 16 + li] = f2bf_u(fmaxf(acc1[t8][reg] + bv, 0.f));
  }
  short8 aK2[4];
#pragma unroll
  for (int k4 = 0; k4 < 4; ++k4) aK2[k4] = *(const short8*)&hidB[r0 + li][k4 * 32 + quad * 8];
  floatx4 acc2[8];
#pragma unroll
  for (int t8 = 0; t8 < 8; ++t8) acc2[t8] = (floatx4){0.f, 0.f, 0.f, 0.f};
#pragma unroll
  for (int t8 = 0; t8 < 8; ++t8) {
    const unsigned short* bp = gw2t + (size_t)(t8 * 16 + li) * 128 + quad * 8;
#pragma unroll
    for (int k4 = 0; k4 < 4; ++k4) {
      short8 bf = *(const short8*)(bp + k4 * 32);
      acc2[t8] = __builtin_amdgcn_mfma_f32_16x16x32_bf16(aK2[k4], bf, acc2[t8], 0, 0, 0);
    }
  }
  float gv[8], blv[8], b2v[8];
#pragma unroll
  for (int t8 = 0; t8 < 8; ++t8) {
    int col = t8 * 16 + li;
    gv[t8] = g[col]; blv[t8] = bln[col]; b2v[t8] = gb2[col];
  }
#pragma unroll
  for (int reg = 0; reg < 4; ++reg) {
    int row = node0 + r0 + quad * 4 + reg;
    float v[8], s = 0.f, s2 = 0.f;
#pragma unroll
    for (int t8 = 0; t8 < 8; ++t8) {
      float xv = x[(size_t)row * C_ + t8 * 16 + li];
      v[t8] = acc2[t8][reg] + b2v[t8] + xv;
      s += v[t8]; s2 += v[t8] * v[t8];
    }
#pragma unroll
    for (int m = 1; m <= 8; m <<= 1) { s += __shfl_xor(s, m); s2 += __shfl_xor(s2, m); }
    float mu = s * (1.0f / C_);
    float var = s2 * (1.0f / C_) - mu * mu;
    float inv = rsqrtf(var + LNE);
#pragma unroll
    for (int t8 = 0; t8 < 8; ++t8)
      hl[(size_t)row * C_ + t8 * 16 + li] = (v[t8] - mu) * inv * gv[t8] + blv[t8];
  }
}

// ------------- MFMA QKV: qkvb = bf16(x @ Wqkv + b) -------------
__global__ __launch_bounds__(256) void k_qkv_mfma(
    const float* __restrict__ x, const unsigned short* __restrict__ qkvt,
    const float* __restrict__ b, unsigned short* __restrict__ qkvb) {
  __shared__ unsigned short inL[64][136];
  int tid = threadIdx.x;
  int row0 = blockIdx.x * 64;
#pragma unroll
  for (int i = 0; i < 8; ++i) {
    int p = i * 256 + tid;
    int r = p >> 5, c4 = p & 31;
    float4 xa = *(const float4*)(x + (size_t)(row0 + r) * C_ + c4 * 4);
    ushort4 u;
    u.x = f2bf_u(xa.x); u.y = f2bf_u(xa.y); u.z = f2bf_u(xa.z); u.w = f2bf_u(xa.w);
    *(ushort4*)&inL[r][c4 * 4] = u;
  }
  __syncthreads();
  int lane = tid & 63, w = tid >> 6, li = lane & 15, quad = lane >> 4;
  int r0 = w * 16;
  short8 aK[4];
#pragma unroll
  for (int k4 = 0; k4 < 4; ++k4) aK[k4] = *(const short8*)&inL[r0 + li][k4 * 32 + quad * 8];
  floatx4 acc[24];
#pragma unroll
  for (int t8 = 0; t8 < 24; ++t8) acc[t8] = (floatx4){0.f, 0.f, 0.f, 0.f};
#pragma unroll
  for (int t8 = 0; t8 < 24; ++t8) {
    const unsigned short* bp = qkvt + (size_t)(t8 * 16 + li) * 128 + quad * 8;
#pragma unroll
    for (int k4 = 0; k4 < 4; ++k4) {
      short8 bf = *(const short8*)(bp + k4 * 32);
      acc[t8] = __builtin_amdgcn_mfma_f32_16x16x32_bf16(aK[k4], bf, acc[t8], 0, 0, 0);
    }
  }
#pragma unroll
  for (int t8 = 0; t8 < 24; ++t8) {
    int col = t8 * 16 + li;
    float bv = b[col];
#pragma unroll
    for (int reg = 0; reg < 4; ++reg) {
      int row = row0 + r0 + quad * 4 + reg;
      qkvb[(size_t)row * 384 + col] = f2bf_u(acc[t8][reg] + bv);
    }
  }
}

// ------------- MFMA flash attention -------------
__global__ __launch_bounds__(256) void k_attn_mfma(const unsigned short* __restrict__ qkvb,
                                                   float* __restrict__ attno) {
  __shared__ unsigned short kL[2][32][40];
  __shared__ unsigned short vT[2][32][40];
  __shared__ unsigned short pL[4][16][40];
  int tid = threadIdx.x;
  int lane = tid & 63;
  int w = tid >> 6;
  int li = lane & 15;
  int quad = lane >> 4;
  int bid = blockIdx.x;
  int qt = bid & 15;
  int h = (bid >> 4) & 3;
  int b = bid >> 6;
  int qbase = b * S_ + qt * 64 + w * 16;

  short8 qA = *(const short8*)(qkvb + (size_t)(qbase + li) * 384 + h * 32 + quad * 8);

  floatx4 o0 = {0.f, 0.f, 0.f, 0.f}, o1 = {0.f, 0.f, 0.f, 0.f};
  float mreg[4] = {-1e30f, -1e30f, -1e30f, -1e30f};
  float lreg[4] = {0.f, 0.f, 0.f, 0.f};
  const float scale = 0.17677669529663687f;

  int half = tid >> 7;
  int tt = tid & 127;
  int j = tt >> 2;
  int seg = tt & 3;

  for (int kc = 0; kc < 32; ++kc) {
    int buf = kc & 1;
    {
      int node = b * S_ + kc * 32 + j;
      const unsigned short* p = qkvb + (size_t)node * 384 + (half ? 256 : 128) + h * 32 + seg * 8;
      short8 val = *(const short8*)p;
      if (half == 0) {
        *(short8*)&kL[buf][j][seg * 8] = val;
      } else {
#pragma unroll
        for (int i = 0; i < 8; ++i) vT[buf][seg * 8 + i][j] = (unsigned short)val[i];
      }
    }
    __syncthreads();
    short8 kB0 = *(const short8*)&kL[buf][li][quad * 8];
    short8 kB1 = *(const short8*)&kL[buf][16 + li][quad * 8];
    floatx4 z = {0.f, 0.f, 0.f, 0.f};
    floatx4 s0 = __builtin_amdgcn_mfma_f32_16x16x32_bf16(qA, kB0, z, 0, 0, 0);
    floatx4 s1 = __builtin_amdgcn_mfma_f32_16x16x32_bf16(qA, kB1, z, 0, 0, 0);
#pragma unroll
    for (int r = 0; r < 4; ++r) {
      float a0 = s0[r] * scale, a1 = s1[r] * scale;
      float cm = fmaxf(a0, a1);
#pragma unroll
      for (int msk = 1; msk <= 8; msk <<= 1) cm = fmaxf(cm, __shfl_xor(cm, msk));
      float mn = fmaxf(mreg[r], cm);
      float al = __expf(mreg[r] - mn);
      mreg[r] = mn;
      float p0 = __expf(a0 - mn), p1 = __expf(a1 - mn);
      float rs = p0 + p1;
#pragma unroll
      for (int msk = 1; msk <= 8; msk <<= 1) rs += __shfl_xor(rs, msk);
      lreg[r] = lreg[r] * al + rs;
      o0[r] *= al;
      o1[r] *= al;
      pL[w][quad * 4 + r][li] = f2bf_u(p0);
      pL[w][quad * 4 + r][16 + li] = f2bf_u(p1);
    }
    __syncthreads();
    short8 pA  = *(const short8*)&pL[w][li][quad * 8];
    short8 vB0 = *(const short8*)&vT[buf][li][quad * 8];
    short8 vB1 = *(const short8*)&vT[buf][16 + li][quad * 8];
    o0 = __builtin_amdgcn_mfma_f32_16x16x32_bf16(pA, vB0, o0, 0, 0, 0);
    o1 = __builtin_amdgcn_mfma_f32_16x16x32_bf16(pA, vB1, o1, 0, 0, 0);
  }
#pragma unroll
  for (int r = 0; r < 4; ++r) {
    float inv = 1.0f / lreg[r];
    size_t row = (size_t)(qbase + quad * 4 + r);
    attno[row * C_ + h * 32 + li] = o0[r] * inv;
    attno[row * C_ + h * 32 + 16 + li] = o1[r] * inv;
  }
}

// ------------- MFMA attn out proj + LN2 -------------
__global__ __launch_bounds__(256) void k_attnout_mfma(
    const float* __restrict__ attno, const float* __restrict__ x,
    const unsigned short* __restrict__ wt, const float* __restrict__ b,
    const float* __restrict__ g, const float* __restrict__ bln,
    float* __restrict__ ha) {
  __shared__ unsigned short inL[64][136];
  int tid = threadIdx.x;
  int row0 = blockIdx.x * 64;
#pragma unroll
  for (int i = 0; i < 8; ++i) {
    int p = i * 256 + tid;
    int r = p >> 5, c4 = p & 31;
    float4 xa = *(const float4*)(attno + (size_t)(row0 + r) * C_ + c4 * 4);
    ushort4 u;
    u.x = f2bf_u(xa.x); u.y = f2bf_u(xa.y); u.z = f2bf_u(xa.z); u.w = f2bf_u(xa.w);
    *(ushort4*)&inL[r][c4 * 4] = u;
  }
  __syncthreads();
  int lane = tid & 63, w = tid >> 6, li = lane & 15, quad = lane >> 4;
  int r0 = w * 16;
  short8 aK[4];
#pragma unroll
  for (int k4 = 0; k4 < 4; ++k4) aK[k4] = *(const short8*)&inL[r0 + li][k4 * 32 + quad * 8];
  floatx4 acc[8];
#pragma unroll
  for (int t8 = 0; t8 < 8; ++t8) acc[t8] = (floatx4){0.f, 0.f, 0.f, 0.f};
#pragma unroll
  for (int t8 = 0; t8 < 8; ++t8) {
    const unsigned short* bp = wt + (size_t)(t8 * 16 + li) * 128 + quad * 8;
#pragma unroll
    for (int k4 = 0; k4 < 4; ++k4) {
      short8 bf = *(const short8*)(bp + k4 * 32);
      acc[t8] = __builtin_amdgcn_mfma_f32_16x16x32_bf16(aK[k4], bf, acc[t8], 0, 0, 0);
    }
  }
  float gv[8], blv[8], bv[8];
#pragma unroll
  for (int t8 = 0; t8 < 8; ++t8) {
    int col = t8 * 16 + li;
    gv[t8] = g[col]; blv[t8] = bln[col]; bv[t8] = b[col];
  }
#pragma unroll
  for (int reg = 0; reg < 4; ++reg) {
    int row = row0 + r0 + quad * 4 + reg;
    float v[8], s = 0.f, s2 = 0.f;
#pragma unroll
    for (int t8 = 0; t8 < 8; ++t8) {
      float xv = x[(size_t)row * C_ + t8 * 16 + li];
      v[t8] = acc[t8][reg] + bv[t8] + xv;
      s += v[t8]; s2 += v[t8] * v[t8];
    }
#pragma unroll
    for (int m = 1; m <= 8; m <<= 1) { s += __shfl_xor(s, m); s2 += __shfl_xor(s2, m); }
    float mu = s * (1.0f / C_);
    float var = s2 * (1.0f / C_) - mu * mu;
    float inv = rsqrtf(var + LNE);
#pragma unroll
    for (int t8 = 0; t8 < 8; ++t8)
      ha[(size_t)row * C_ + t8 * 16 + li] = (v[t8] - mu) * inv * gv[t8] + blv[t8];
  }
}

// ------------- MFMA FFN -------------
__global__ __launch_bounds__(256) void k_ffn_mfma(
    const float* __restrict__ hl, const float* __restrict__ ha,
    float* __restrict__ x,
    const unsigned short* __restrict__ w1t, const float* __restrict__ b1,
    const unsigned short* __restrict__ w2t, const float* __restrict__ b2,
    const float* __restrict__ g, const float* __restrict__ bln) {
  __shared__ unsigned short inL[64][136];
  __shared__ unsigned short hidL[64][264];
  int tid = threadIdx.x;
  int row0 = blockIdx.x * 64;
#pragma unroll
  for (int i = 0; i < 8; ++i) {
    int p = i * 256 + tid;
    int r = p >> 5, c4 = p & 31;
    float4 a = *(const float4*)(hl + (size_t)(row0 + r) * C_ + c4 * 4);
    float4 bq = *(const float4*)(ha + (size_t)(row0 + r) * C_ + c4 * 4);
    ushort4 u;
    u.x = f2bf_u(a.x + bq.x); u.y = f2bf_u(a.y + bq.y);
    u.z = f2bf_u(a.z + bq.z); u.w = f2bf_u(a.w + bq.w);
    *(ushort4*)&inL[r][c4 * 4] = u;
  }
  __syncthreads();
  int lane = tid & 63, w = tid >> 6, li = lane & 15, quad = lane >> 4;
  int r0 = w * 16;
  short8 aK[4];
#pragma unroll
  for (int k4 = 0; k4 < 4; ++k4) aK[k4] = *(const short8*)&inL[r0 + li][k4 * 32 + quad * 8];
  floatx4 acc1[16];
#pragma unroll
  for (int t8 = 0; t8 < 16; ++t8) acc1[t8] = (floatx4){0.f, 0.f, 0.f, 0.f};
#pragma unroll
  for (int t8 = 0; t8 < 16; ++t8) {
    const unsigned short* bp = w1t + (size_t)(t8 * 16 + li) * 128 + quad * 8;
#pragma unroll
    for (int k4 = 0; k4 < 4; ++k4) {
      short8 bf = *(const short8*)(bp + k4 * 32);
      acc1[t8] = __builtin_amdgcn_mfma_f32_16x16x32_bf16(aK[k4], bf, acc1[t8], 0, 0, 0);
    }
  }
#pragma unroll
  for (int t8 = 0; t8 < 16; ++t8) {
    float bv = b1[t8 * 16 + li];
#pragma unroll
    for (int reg = 0; reg < 4; ++reg)
      hidL[r0 + quad * 4 + reg][t8 * 16 + li] = f2bf_u(gelu_tanh(acc1[t8][reg] + bv));
  }
  short8 aK2[8];
#pragma unroll
  for (int k4 = 0; k4 < 8; ++k4) aK2[k4] = *(const short8*)&hidL[r0 + li][k4 * 32 + quad * 8];
  floatx4 acc2[8];
#pragma unroll
  for (int t8 = 0; t8 < 8; ++t8) acc2[t8] = (floatx4){0.f, 0.f, 0.f, 0.f};
#pragma unroll
  for (int t8 = 0; t8 < 8; ++t8) {
    const unsigned short* bp = w2t + (size_t)(t8 * 16 + li) * 256 + quad * 8;
#pragma unroll
    for (int k4 = 0; k4 < 8; ++k4) {
      short8 bf = *(const short8*)(bp + k4 * 32);
      acc2[t8] = __builtin_amdgcn_mfma_f32_16x16x32_bf16(aK2[k4], bf, acc2[t8], 0, 0, 0);
    }
  }
  float gv[8], blv[8], b2v[8];
#pragma unroll
  for (int t8 = 0; t8 < 8; ++t8) {
    int col = t8 * 16 + li;
    gv[t8] = g[col]; blv[t8] = bln[col]; b2v[t8] = b2[col];
  }
#pragma unroll
  for (int reg = 0; reg < 4; ++reg) {
    int row = row0 + r0 + quad * 4 + reg;
    float v[8], s = 0.f, s2 = 0.f;
#pragma unroll
    for (int t8 = 0; t8 < 8; ++t8) {
      size_t idx = (size_t)row * C_ + t8 * 16 + li;
      float outv = hl[idx] + ha[idx];
      v[t8] = acc2[t8][reg] + b2v[t8] + outv;
      s += v[t8]; s2 += v[t8] * v[t8];
    }
#pragma unroll
    for (int m = 1; m <= 8; m <<= 1) { s += __shfl_xor(s, m); s2 += __shfl_xor(s2, m); }
    float mu = s * (1.0f / C_);
    float var = s2 * (1.0f / C_) - mu * mu;
    float inv = rsqrtf(var + LNE);
#pragma unroll
    for (int t8 = 0; t8 < 8; ++t8) {
      size_t idx = (size_t)row * C_ + t8 * 16 + li;
      x[idx] = x[idx] + (v[t8] - mu) * inv * gv[t8] + blv[t8];
    }
  }
}

// ------------- post MLP (scalar fp32) -------------
__global__ void k_post(float* __restrict__ x,
                       const float* __restrict__ w1, const float* __restrict__ b1,
                       const float* __restrict__ w2, const float* __restrict__ b2) {
  __shared__ float inL[4][C_];
  __shared__ float hidL[4][C_];
  int t = threadIdx.x;
  int row0 = blockIdx.x * 4;
  float xv[4];
#pragma unroll
  for (int r = 0; r < 4; ++r) {
    size_t idx = (size_t)(row0 + r) * C_ + t;
    xv[r] = x[idx];
    inL[r][t] = xv[r];
  }
  __syncthreads();
  float acc[4];
  float bb = b1[t];
#pragma unroll
  for (int r = 0; r < 4; ++r) acc[r] = bb;
  for (int k = 0; k < C_; ++k) {
    float wv = w1[k * C_ + t];
#pragma unroll
    for (int r = 0; r < 4; ++r) acc[r] += inL[r][k] * wv;
  }
#pragma unroll
  for (int r = 0; r < 4; ++r) hidL[r][t] = fmaxf(acc[r], 0.0f);
  __syncthreads();
  float bb2 = b2[t];
#pragma unroll
  for (int r = 0; r < 4; ++r) acc[r] = bb2;
  for (int k = 0; k < C_; ++k) {
    float wv = w2[k * C_ + t];
#pragma unroll
    for (int r = 0; r < 4; ++r) acc[r] += hidL[r][k] * wv;
  }
#pragma unroll
  for (int r = 0; r < 4; ++r) {
    size_t idx = (size_t)(row0 + r) * C_ + t;
    x[idx] = xv[r] + acc[r];
  }
}

// ------------- mean pool per graph -------------
__global__ void k_pool(const float* __restrict__ x, float* __restrict__ gmean) {
  int t = threadIdx.x;
  int b = blockIdx.x;
  float s = 0.0f;
  for (int sidx = 0; sidx < S_; ++sidx) s += x[((size_t)b * S_ + sidx) * C_ + t];
  gmean[b * C_ + t] = s * (1.0f / S_);
}

// ------------- readout -------------
__global__ void k_readout(const float* __restrict__ gmean,
                          const float* __restrict__ w1, const float* __restrict__ b1,
                          const float* __restrict__ w2, const float* __restrict__ b2,
                          float* __restrict__ out) {
  __shared__ float gL[C_];
  __shared__ float red[C_];
  int t = threadIdx.x;
  int b = blockIdx.x;
  gL[t] = gmean[b * C_ + t];
  __syncthreads();
  float acc = b1[t];
  for (int k = 0; k < C_; ++k) acc += gL[k] * w1[k * C_ + t];
  float hid = fmaxf(acc, 0.0f);
  float part = hid * w2[t];
  float tot = block_sum128(part, red, t);
  if (t == 0) out[b] = tot + b2[0];
}

}  // namespace

extern "C" void kernel_launch(void* const* d_in, const int* in_sizes, int n_in,
                              void* d_out, int out_size, void* d_ws, size_t ws_size,
                              hipStream_t stream) {
  const float* in_x      = (const float*)d_in[0];
  const int*   edge_idx  = (const int*)d_in[1];
  const float* edge_attr = (const float*)d_in[3];
  const float* lap_pe    = (const float*)d_in[4];
  const float* node_w1 = (const float*)d_in[5];
  const float* node_b1 = (const float*)d_in[6];
  const float* node_w2 = (const float*)d_in[7];
  const float* node_b2 = (const float*)d_in[8];
  const float* edge_w1 = (const float*)d_in[9];
  const float* edge_b1 = (const float*)d_in[10];
  const float* edge_w2 = (const float*)d_in[11];
  const float* edge_b2 = (const float*)d_in[12];
  const float* eps     = (const float*)d_in[13];
  const float* gin_w1  = (const float*)d_in[14];
  const float* gin_b1  = (const float*)d_in[15];
  const float* gin_w2  = (const float*)d_in[16];
  const float* gin_b2  = (const float*)d_in[17];
  const float* elin_w  = (const float*)d_in[18];
  const float* elin_b  = (const float*)d_in[19];
  const float* aqkv_w  = (const float*)d_in[20];
  const float* aqkv_b  = (const float*)d_in[21];
  const float* aout_w  = (const float*)d_in[22];
  const float* aout_b  = (const float*)d_in[23];
  const float* mlp_w1  = (const float*)d_in[24];
  const float* mlp_b1  = (const float*)d_in[25];
  const float* mlp_w2  = (const float*)d_in[26];
  const float* mlp_b2  = (const float*)d_in[27];
  const float* ln1_g   = (const float*)d_in[28];
  const float* ln1_b   = (const float*)d_in[29];
  const float* ln2_g   = (const float*)d_in[30];
  const float* ln2_b   = (const float*)d_in[31];
  const float* ln3_g   = (const float*)d_in[32];
  const float* ln3_b   = (const float*)d_in[33];
  const float* post_w1 = (const float*)d_in[34];
  const float* post_b1 = (const float*)d_in[35];
  const float* post_w2 = (const float*)d_in[36];
  const float* post_b2 = (const float*)d_in[37];
  const float* ro_w1   = (const float*)d_in[38];
  const float* ro_b1   = (const float*)d_in[39];
  const float* ro_w2   = (const float*)d_in[40];
  const float* ro_b2   = (const float*)d_in[41];

  const int* src = edge_idx;
  const int* dst = edge_idx + E_;

  // Workspace: x NC | qkvb bf16 N*384 | hl NC | attno NC | fb2 | fw2tb | wt | sort ints (~78 MB)
  float* ws = (float*)d_ws;
  float* x     = ws;                                  // N*C
  unsigned short* qkvb = (unsigned short*)(x + (size_t)N_ * C_);  // N*384 bf16
  float* hl    = x + (size_t)N_ * C_ + (size_t)N_ * 192;          // N*C
  float* attno = hl + (size_t)N_ * C_;                // N*C
  float* ha    = attno;                               // in-place
  float* fb2   = attno + (size_t)N_ * C_;             // L*C floats
  unsigned short* fw2tb = (unsigned short*)(fb2 + 4 * C_);  // L*C*C bf16
  unsigned short* wt = fw2tb + (size_t)4 * C_ * C_;   // 655360 bf16 node weights
  int* hist    = (int*)(wt + 655360);                 // 32768 (becomes cursor)
  int* binStart = hist + 32768;                       // 32769
  int* perm    = binStart + 32769;                    // E
  float* gmean = hl;                                  // alias

  float* out = (float*)d_out;

  dim3 blk(128);
  const size_t LWS = 163840;

  // --- one-time per launch: weight prep + edge sort by dst ---
  k_fuse_w<<<4 * (C_ + 1), blk, 0, stream>>>(edge_w2, edge_b2, elin_w, elin_b, fw2tb, fb2);
  k_prep<<<4 * 1152, blk, 0, stream>>>(gin_w1, gin_w2, aqkv_w, aout_w, mlp_w1, mlp_w2, wt);
  k_zero<<<(32768 / 4 + 255) / 256, 256, 0, stream>>>((float4*)hist, 32768 / 4);
  k_count<<<E_ / 256, 256, 0, stream>>>(dst, hist);
  k_scan<<<1, 1024, 0, stream>>>(hist, binStart);
  k_scatter<<<E_ / 256, 256, 0, stream>>>(dst, hist, perm);
  k_node_enc<<<N_ / 4, blk, 0, stream>>>(in_x, lap_pe, node_w1, node_b1, node_w2, node_b2, x);

  for (int i = 0; i < 4; ++i) {
    const unsigned short* wl = wt + (size_t)i * LWS;
    k_edge_gin<<<N_ / 64, 256, 0, stream>>>(edge_attr, x, src, dst, perm, binStart,
                                            edge_w1, edge_b1,
                                            fw2tb + (size_t)i * C_ * C_, fb2 + i * C_,
                                            wl + 0, gin_b1 + i * C_,
                                            wl + 16384, gin_b2 + i * C_,
                                            ln1_g + i * C_, ln1_b + i * C_, eps, i, hl);
    k_qkv_mfma<<<N_ / 64, 256, 0, stream>>>(x, wl + 32768, aqkv_b + i * 384, qkvb);
    k_attn_mfma<<<B_ * 4 * 16, 256, 0, stream>>>(qkvb, attno);
    k_attnout_mfma<<<N_ / 64, 256, 0, stream>>>(attno, x,
                                                wl + 81920, aout_b + i * C_,
                                                ln2_g + i * C_, ln2_b + i * C_, ha);
    k_ffn_mfma<<<N_ / 64, 256, 0, stream>>>(hl, ha, x,
                                            wl + 98304, mlp_b1 + i * 256,
                                            wl + 131072, mlp_b2 + i * C_,
                                            ln3_g + i * C_, ln3_b + i * C_);
  }

  k_post<<<N_ / 4, blk, 0, stream>>>(x, post_w1, post_b1, post_w2, post_b2);
  k_pool<<<B_, blk, 0, stream>>>(x, gmean);
  k_readout<<<B_, blk, 0, stream>>>(gmean, ro_w1, ro_b1, ro_w2, ro_b2, out);
}